// Round 1
// baseline (136.715 us; speedup 1.0000x reference)
//
#include <hip/hip_runtime.h>
#include <stdint.h>

// Triplet log-ratio loss — LDS dimension-slice rewrite.
// R9 analysis: main kernel (~36us) is bound by the random L2 gather path
// (~2.7 TB/s effective, ~7x above every component roofline; contention curve
// flat after grid 2048->1024->512). Fix: eliminate the gathers entirely.
//   prep: x (16384,128) fp32 -> int4 nibbles, stored SLICE-MAJOR:
//         xqs[s][r] = packed u32 of dims [8s,8s+8) of row r  (16 slices, 1 MB).
//   main: 256 blocks x 512 thr; each thread owns 4 triplets, keeps 5 int
//         accumulators per triplet (AA,PP,NN,AP,AN). 16 passes: stage slice s
//         (64 KB) into LDS (reg-staged, issue-early/write-late so HBM/L2
//         latency hides under compute), then 12 random ds_read_b32 + 20
//         v_dot8_i32_i4 per thread. Indices live in VGPRs across all passes.
//         Finish: d_ap/d_an = (6/7)^2 * int sums, logs, block reduce, atomic.

constexpr int DIM = 128;
constexpr int NSL = DIM / 8;   // 16 dimension-slices, one packed u32 (8x int4) per row

#if defined(__has_builtin)
#  if __has_builtin(__builtin_amdgcn_sdot4)
#    define HAS_SDOT4 1
#  endif
#  if __has_builtin(__builtin_amdgcn_sdot8)
#    define HAS_SDOT8 1
#  endif
#endif

__device__ inline int dot4i8(uint32_t a, uint32_t b, int c) {
#ifdef HAS_SDOT4
    return __builtin_amdgcn_sdot4((int)a, (int)b, c, false);
#else
    #pragma unroll
    for (int k = 0; k < 32; k += 8)
        c += ((int)(int8_t)(a >> k)) * ((int)(int8_t)(b >> k));
    return c;
#endif
}

// 8-element signed-int4 dot product: c += sum_i sext4(a_i)*sext4(b_i)
__device__ inline int dot8n(uint32_t a, uint32_t b, int c) {
#ifdef HAS_SDOT8
    return __builtin_amdgcn_sdot8((int)a, (int)b, c, false);
#else
    // nibble-plane fallback: bytes hold 16*q, so result carries a 256x factor
    uint32_t ae = (a << 4) & 0xF0F0F0F0u, ao = a & 0xF0F0F0F0u;
    uint32_t be = (b << 4) & 0xF0F0F0F0u, bo = b & 0xF0F0F0F0u;
    c = dot4i8(ae, be, c);
    return dot4i8(ao, bo, c);
#endif
}

#ifdef HAS_SDOT8
constexpr float SC = 36.0f / 49.0f;            // (6/7)^2, q = x*7/6
#else
constexpr float SC = 36.0f / 49.0f / 256.0f;   // fallback dots are 256x
#endif

constexpr float QK = 7.0f / 6.0f;

// ---------- prep: fp32 -> int4, slice-major layout (+ zero out). 4 thr/row ----
__global__ __launch_bounds__(256) void prep_q4s_kernel(
    const float4* __restrict__ x4, uint32_t* __restrict__ xqs,
    float* __restrict__ out, int nrows)
{
    if (blockIdx.x == 0 && threadIdx.x == 0) *out = 0.0f;
    const int gid = blockIdx.x * 256 + threadIdx.x;
    if (gid >= nrows * 4) return;
    const int r = gid >> 2, j = gid & 3;       // row, 32-dim chunk
    const int base = gid * 8;                  // float4 index
    uint32_t w[4];
    #pragma unroll
    for (int d = 0; d < 4; ++d) {
        const float4 f0 = x4[base + 2 * d];
        const float4 f1 = x4[base + 2 * d + 1];
        uint32_t u = 0;
        const float* f = &f0.x;
        #pragma unroll
        for (int jj = 0; jj < 4; ++jj) {
            int q = max(-7, min(7, __float2int_rn(f[jj] * QK)));
            u |= (uint32_t)(q & 15) << (4 * jj);
        }
        const float* g = &f1.x;
        #pragma unroll
        for (int jj = 0; jj < 4; ++jj) {
            int q = max(-7, min(7, __float2int_rn(g[jj] * QK)));
            u |= (uint32_t)(q & 15) << (4 * jj + 16);
        }
        w[d] = u;
    }
    // word d covers dims [32j+8d, 32j+8d+8) -> slice index 4j+d, slice-major store
    #pragma unroll
    for (int d = 0; d < 4; ++d)
        xqs[(4 * j + d) * nrows + r] = w[d];
}

// ---------- main: LDS slice passes, per-thread int accumulators --------------
__global__ __launch_bounds__(512, 2) void triplet_lds_kernel(
    const uint32_t* __restrict__ xqs, const int* __restrict__ trip,
    float* __restrict__ out, int T)
{
    constexpr int NR = 16384;                  // rows (guarded at launch)
    __shared__ uint32_t sl[NR];                // 64 KB: one slice, all rows
    const int tid = threadIdx.x;
    const int t0 = (blockIdx.x * 512 + tid) * 4;

    // ---- load 12 indices once; they live in VGPRs for all 16 passes ----
    int iA[4], iP[4], iN[4];
    bool val[4];
    #pragma unroll
    for (int j = 0; j < 4; ++j) val[j] = (t0 + j < T);
    if (val[3]) {
        const int4* tp = (const int4*)(trip + 3 * t0);   // 48-B aligned
        const int4 w0 = tp[0], w1 = tp[1], w2 = tp[2];
        iA[0] = w0.x; iP[0] = w0.y; iN[0] = w0.z;
        iA[1] = w0.w; iP[1] = w1.x; iN[1] = w1.y;
        iA[2] = w1.z; iP[2] = w1.w; iN[2] = w2.x;
        iA[3] = w2.y; iP[3] = w2.z; iN[3] = w2.w;
    } else {
        #pragma unroll
        for (int j = 0; j < 4; ++j) {
            const int b = val[j] ? 3 * (t0 + j) : 0;
            iA[j] = trip[b]; iP[j] = trip[b + 1]; iN[j] = trip[b + 2];
        }
    }

    int AA[4] = {0,0,0,0}, PP[4] = {0,0,0,0}, NN[4] = {0,0,0,0};
    int AP[4] = {0,0,0,0}, AN[4] = {0,0,0,0};

    // ---- stage slice 0 (64 KB = 8 x uint4 per thread), then loop passes ----
    uint4 st[8];
    {
        const uint4* src = (const uint4*)xqs;
        #pragma unroll
        for (int c = 0; c < 8; ++c) st[c] = src[c * 512 + tid];
        uint4* dst = (uint4*)sl;
        #pragma unroll
        for (int c = 0; c < 8; ++c) dst[c * 512 + tid] = st[c];
    }
    __syncthreads();

    for (int s = 0; s < NSL; ++s) {
        // issue next slice's global loads EARLY: latency hides under compute
        if (s + 1 < NSL) {
            const uint4* src = (const uint4*)(xqs + (size_t)(s + 1) * NR);
            #pragma unroll
            for (int c = 0; c < 8; ++c) st[c] = src[c * 512 + tid];
        }
        // compute this pass: 12 random LDS b32 reads, 20 int4-dot8s
        #pragma unroll
        for (int j = 0; j < 4; ++j) {
            const uint32_t wa = sl[iA[j]];
            const uint32_t wp = sl[iP[j]];
            const uint32_t wn = sl[iN[j]];
            AA[j] = dot8n(wa, wa, AA[j]);
            PP[j] = dot8n(wp, wp, PP[j]);
            NN[j] = dot8n(wn, wn, NN[j]);
            AP[j] = dot8n(wa, wp, AP[j]);
            AN[j] = dot8n(wa, wn, AN[j]);
        }
        if (s + 1 < NSL) {
            __syncthreads();                   // all reads of slice s done
            uint4* dst = (uint4*)sl;
            #pragma unroll
            for (int c = 0; c < 8; ++c) dst[c * 512 + tid] = st[c];
            __syncthreads();                   // slice s+1 visible
        }
    }

    // ---- finish: log terms, block reduce, one atomic ----
    float acc = 0.0f;
    #pragma unroll
    for (int j = 0; j < 4; ++j) {
        const float dap = SC * (float)(AA[j] + PP[j] - 2 * AP[j]);
        const float dan = SC * (float)(AA[j] + NN[j] - 2 * AN[j]);
        const float numer = fmaxf(1.0f + dan, 1e-8f);
        const float denom = fmaxf(2.0f + dap + dan, 1e-8f);
        acc += val[j] ? (__log2f(denom) - __log2f(numer)) : 0.0f;
    }
    acc *= 0.69314718055994531f;               // log2 -> ln
    #pragma unroll
    for (int off = 1; off < 64; off <<= 1)
        acc += __shfl_xor(acc, off, 64);

    __syncthreads();                           // done reading sl: reuse as scratch
    float* wsf = (float*)sl;
    if ((tid & 63) == 0) wsf[tid >> 6] = acc;
    __syncthreads();
    if (tid == 0) {
        float s8 = 0.0f;
        #pragma unroll
        for (int w = 0; w < 8; ++w) s8 += wsf[w];
        atomicAdd(out, s8);
    }
}

// ---------- fallback (fp32 direct) if ws too small / unexpected shape --------
__global__ __launch_bounds__(256) void triplet_f32_kernel(
    const float* __restrict__ x, const int* __restrict__ trip,
    float* __restrict__ out, int T)
{
    const int lane = threadIdx.x & 63;
    const int g = lane >> 5, jl = lane & 31;
    const int wib = threadIdx.x >> 6;
    const int gw = blockIdx.x * 4 + wib;
    const int nW = gridDim.x * 4;
    const float4* __restrict__ x4 = (const float4*)x;

    float acc = 0.0f;
    const int npairs = (T + 1) >> 1;
    for (int i = gw; i < npairs; i += nW) {
        const int t = 2 * i + g;
        if (t >= T) continue;
        const int a = trip[3*t], p = trip[3*t+1], n = trip[3*t+2];
        const float4 va = x4[a * 32 + jl];
        const float4 vp = x4[p * 32 + jl];
        const float4 vn = x4[n * 32 + jl];
        float d0 = va.x - vp.x, d1 = va.y - vp.y, d2 = va.z - vp.z, d3 = va.w - vp.w;
        float dap = d0*d0 + d1*d1 + d2*d2 + d3*d3;
        d0 = va.x - vn.x; d1 = va.y - vn.y; d2 = va.z - vn.z; d3 = va.w - vn.w;
        float dan = d0*d0 + d1*d1 + d2*d2 + d3*d3;
        #pragma unroll
        for (int off = 1; off < 32; off <<= 1) {
            dap += __shfl_xor(dap, off, 64);
            dan += __shfl_xor(dan, off, 64);
        }
        const float numer = fmaxf(1.0f + dan, 1e-8f);
        const float denom = fmaxf(2.0f + dap + dan, 1e-8f);
        acc += (jl == 0) ? (__logf(denom) - __logf(numer)) : 0.0f;
    }
    #pragma unroll
    for (int off = 1; off < 64; off <<= 1)
        acc += __shfl_xor(acc, off, 64);
    __shared__ float wsum[4];
    if (lane == 0) wsum[wib] = acc;
    __syncthreads();
    if (threadIdx.x == 0)
        atomicAdd(out, wsum[0] + wsum[1] + wsum[2] + wsum[3]);
}

extern "C" void kernel_launch(void* const* d_in, const int* in_sizes, int n_in,
                              void* d_out, int out_size, void* d_ws, size_t ws_size,
                              hipStream_t stream) {
    const float* x  = (const float*)d_in[0];
    const int* trip = (const int*)d_in[1];
    float* out      = (float*)d_out;
    const int T     = in_sizes[1] / 3;
    const int nrows = in_sizes[0] / DIM;

    const size_t xqs_bytes = (size_t)nrows * (DIM / 2);   // 1 MB slice-major table
    if (nrows == 16384 && ws_size >= xqs_bytes) {
        uint32_t* xqs = (uint32_t*)d_ws;
        const int cblocks = (nrows * 4 + 255) / 256;
        prep_q4s_kernel<<<cblocks, 256, 0, stream>>>((const float4*)x, xqs, out, nrows);
        const int blocks = (T + 2047) / 2048;             // 512 thr x 4 triplets
        triplet_lds_kernel<<<blocks, 512, 0, stream>>>(xqs, trip, out, T);
    } else {
        (void)hipMemsetAsync(out, 0, sizeof(float), stream);
        triplet_f32_kernel<<<2048, 256, 0, stream>>>(x, trip, out, T);
    }
}

// Round 2
// 83.345 us; speedup vs baseline: 1.6404x; 1.6404x over previous
//
#include <hip/hip_runtime.h>
#include <stdint.h>

// Triplet log-ratio loss — LDS dimension-slice, v2 (DMA staging).
// R1 post-mortem: reg-staged double buffer (uint4 st[8]) spilled to scratch
// (VGPR_Count 52, WRITE_SIZE 126 MB of scratch traffic, VALUBusy 2.9%) ->
// main kernel 80us. Fix: __builtin_amdgcn_global_load_lds (direct L2->LDS DMA,
// zero VGPR cost) + 2x64KB LDS double buffer, one barrier per pass. The
// barrier's vmcnt(0) drain is exactly the pipeline semantics we want: DMA for
// slice s+1 issued BEFORE the pass-s compute, drained at the pass-end barrier.
//   prep: x (16384,128) fp32 -> int4 nibbles, SLICE-MAJOR:
//         xqs[s][r] = packed u32 of dims [8s,8s+8) of row r (16 slices, 1 MB).
//   main: 256 blocks x 512 thr, 4 triplets/thread, 5 int accs per triplet.
//         16 passes: DMA next slice (8 x global_load_lds dwordx4 per thread),
//         12 random ds_read_b32 + 20 int4-dot8 per thread, barrier.

constexpr int DIM = 128;
constexpr int NSL = DIM / 8;   // 16 dimension-slices, one packed u32 (8x int4) per row
constexpr int NR  = 16384;     // rows (guarded at launch)

#if defined(__has_builtin)
#  if __has_builtin(__builtin_amdgcn_sdot4)
#    define HAS_SDOT4 1
#  endif
#  if __has_builtin(__builtin_amdgcn_sdot8)
#    define HAS_SDOT8 1
#  endif
#  if __has_builtin(__builtin_amdgcn_global_load_lds)
#    define HAS_GLL 1
#  endif
#endif

__device__ inline int dot4i8(uint32_t a, uint32_t b, int c) {
#ifdef HAS_SDOT4
    return __builtin_amdgcn_sdot4((int)a, (int)b, c, false);
#else
    #pragma unroll
    for (int k = 0; k < 32; k += 8)
        c += ((int)(int8_t)(a >> k)) * ((int)(int8_t)(b >> k));
    return c;
#endif
}

// 8-element signed-int4 dot product: c += sum_i sext4(a_i)*sext4(b_i)
__device__ inline int dot8n(uint32_t a, uint32_t b, int c) {
#ifdef HAS_SDOT8
    return __builtin_amdgcn_sdot8((int)a, (int)b, c, false);
#else
    // nibble-plane fallback: bytes hold 16*q, so result carries a 256x factor
    uint32_t ae = (a << 4) & 0xF0F0F0F0u, ao = a & 0xF0F0F0F0u;
    uint32_t be = (b << 4) & 0xF0F0F0F0u, bo = b & 0xF0F0F0F0u;
    c = dot4i8(ae, be, c);
    return dot4i8(ao, bo, c);
#endif
}

#ifdef HAS_SDOT8
constexpr float SC = 36.0f / 49.0f;            // (6/7)^2, q = x*7/6
#else
constexpr float SC = 36.0f / 49.0f / 256.0f;   // fallback dots are 256x
#endif

constexpr float QK = 7.0f / 6.0f;

// ---------- prep: fp32 -> int4, slice-major layout (+ zero out). 4 thr/row ----
__global__ __launch_bounds__(256) void prep_q4s_kernel(
    const float4* __restrict__ x4, uint32_t* __restrict__ xqs,
    float* __restrict__ out, int nrows)
{
    if (blockIdx.x == 0 && threadIdx.x == 0) *out = 0.0f;
    const int gid = blockIdx.x * 256 + threadIdx.x;
    if (gid >= nrows * 4) return;
    const int r = gid >> 2, j = gid & 3;       // row, 32-dim chunk
    const int base = gid * 8;                  // float4 index
    uint32_t w[4];
    #pragma unroll
    for (int d = 0; d < 4; ++d) {
        const float4 f0 = x4[base + 2 * d];
        const float4 f1 = x4[base + 2 * d + 1];
        uint32_t u = 0;
        const float* f = &f0.x;
        #pragma unroll
        for (int jj = 0; jj < 4; ++jj) {
            int q = max(-7, min(7, __float2int_rn(f[jj] * QK)));
            u |= (uint32_t)(q & 15) << (4 * jj);
        }
        const float* g = &f1.x;
        #pragma unroll
        for (int jj = 0; jj < 4; ++jj) {
            int q = max(-7, min(7, __float2int_rn(g[jj] * QK)));
            u |= (uint32_t)(q & 15) << (4 * jj + 16);
        }
        w[d] = u;
    }
    // word d covers dims [32j+8d, 32j+8d+8) -> slice index 4j+d, slice-major store
    #pragma unroll
    for (int d = 0; d < 4; ++d)
        xqs[(4 * j + d) * nrows + r] = w[d];
}

// ---------- main: DMA-staged LDS slice passes, double-buffered ---------------
__global__ __launch_bounds__(512, 2) void triplet_lds2_kernel(
    const uint32_t* __restrict__ xqs, const int* __restrict__ trip,
    float* __restrict__ out, int T)
{
    __shared__ uint32_t sl[2][NR];             // 2 x 64 KB double buffer
    __shared__ float wsum[8];
    const int tid = threadIdx.x;
    const int t0 = (blockIdx.x * 512 + tid) * 4;

    // ---- load 12 indices once; they live in VGPRs for all 16 passes ----
    int iA[4], iP[4], iN[4];
    bool val[4];
    #pragma unroll
    for (int j = 0; j < 4; ++j) val[j] = (t0 + j < T);
    if (val[3]) {
        const int4* tp = (const int4*)(trip + 3 * t0);   // 48-B aligned
        const int4 w0 = tp[0], w1 = tp[1], w2 = tp[2];
        iA[0] = w0.x; iP[0] = w0.y; iN[0] = w0.z;
        iA[1] = w0.w; iP[1] = w1.x; iN[1] = w1.y;
        iA[2] = w1.z; iP[2] = w1.w; iN[2] = w2.x;
        iA[3] = w2.y; iP[3] = w2.z; iN[3] = w2.w;
    } else {
        #pragma unroll
        for (int j = 0; j < 4; ++j) {
            const int b = val[j] ? 3 * (t0 + j) : 0;
            iA[j] = trip[b]; iP[j] = trip[b + 1]; iN[j] = trip[b + 2];
        }
    }

    int AA[4] = {0,0,0,0}, PP[4] = {0,0,0,0}, NN[4] = {0,0,0,0};
    int AP[4] = {0,0,0,0}, AN[4] = {0,0,0,0};

    // stage slice s into buffer b: 64 KB = 64 wave-DMAs of 1 KB, 8 per thread.
    // LDS dest must be wave-uniform base + lane*16 (it is: linear lane order).
    const int wbase = tid & ~63;               // wave-uniform uint4 index base
    auto stage = [&](int b, int s) {
        const uint4* src = (const uint4*)(xqs + (size_t)s * NR);
        uint4* dst = (uint4*)sl[b];
        #pragma unroll
        for (int c = 0; c < 8; ++c) {
#ifdef HAS_GLL
            __builtin_amdgcn_global_load_lds(
                (const __attribute__((address_space(1))) uint32_t*)(src + c * 512 + tid),
                (__attribute__((address_space(3))) uint32_t*)(dst + c * 512 + wbase),
                16, 0, 0);
#else
            dst[c * 512 + tid] = src[c * 512 + tid];   // fallback: sync copy
#endif
        }
    };

    stage(0, 0);
    __syncthreads();                           // vmcnt(0) drain: slice 0 landed

    int cur = 0;
    for (int s = 0; s < NSL; ++s) {
        if (s + 1 < NSL) stage(cur ^ 1, s + 1);    // async DMA, in flight over compute
        const uint32_t* bf = sl[cur];
        #pragma unroll
        for (int j = 0; j < 4; ++j) {
            const uint32_t wa = bf[iA[j]];
            const uint32_t wp = bf[iP[j]];
            const uint32_t wn = bf[iN[j]];
            AA[j] = dot8n(wa, wa, AA[j]);
            PP[j] = dot8n(wp, wp, PP[j]);
            NN[j] = dot8n(wn, wn, NN[j]);
            AP[j] = dot8n(wa, wp, AP[j]);
            AN[j] = dot8n(wa, wn, AN[j]);
        }
        if (s + 1 < NSL) {
            __syncthreads();                   // drains vmcnt: next slice ready;
            cur ^= 1;                          // all reads of slice s also done
        }
    }

    // ---- finish: log terms, block reduce, one atomic ----
    float acc = 0.0f;
    #pragma unroll
    for (int j = 0; j < 4; ++j) {
        const float dap = SC * (float)(AA[j] + PP[j] - 2 * AP[j]);
        const float dan = SC * (float)(AA[j] + NN[j] - 2 * AN[j]);
        const float numer = fmaxf(1.0f + dan, 1e-8f);
        const float denom = fmaxf(2.0f + dap + dan, 1e-8f);
        acc += val[j] ? (__log2f(denom) - __log2f(numer)) : 0.0f;
    }
    acc *= 0.69314718055994531f;               // log2 -> ln
    #pragma unroll
    for (int off = 1; off < 64; off <<= 1)
        acc += __shfl_xor(acc, off, 64);

    if ((tid & 63) == 0) wsum[tid >> 6] = acc;
    __syncthreads();
    if (tid == 0) {
        float s8 = 0.0f;
        #pragma unroll
        for (int w = 0; w < 8; ++w) s8 += wsum[w];
        atomicAdd(out, s8);
    }
}

// ---------- fallback (fp32 direct) if ws too small / unexpected shape --------
__global__ __launch_bounds__(256) void triplet_f32_kernel(
    const float* __restrict__ x, const int* __restrict__ trip,
    float* __restrict__ out, int T)
{
    const int lane = threadIdx.x & 63;
    const int g = lane >> 5, jl = lane & 31;
    const int wib = threadIdx.x >> 6;
    const int gw = blockIdx.x * 4 + wib;
    const int nW = gridDim.x * 4;
    const float4* __restrict__ x4 = (const float4*)x;

    float acc = 0.0f;
    const int npairs = (T + 1) >> 1;
    for (int i = gw; i < npairs; i += nW) {
        const int t = 2 * i + g;
        if (t >= T) continue;
        const int a = trip[3*t], p = trip[3*t+1], n = trip[3*t+2];
        const float4 va = x4[a * 32 + jl];
        const float4 vp = x4[p * 32 + jl];
        const float4 vn = x4[n * 32 + jl];
        float d0 = va.x - vp.x, d1 = va.y - vp.y, d2 = va.z - vp.z, d3 = va.w - vp.w;
        float dap = d0*d0 + d1*d1 + d2*d2 + d3*d3;
        d0 = va.x - vn.x; d1 = va.y - vn.y; d2 = va.z - vn.z; d3 = va.w - vn.w;
        float dan = d0*d0 + d1*d1 + d2*d2 + d3*d3;
        #pragma unroll
        for (int off = 1; off < 32; off <<= 1) {
            dap += __shfl_xor(dap, off, 64);
            dan += __shfl_xor(dan, off, 64);
        }
        const float numer = fmaxf(1.0f + dan, 1e-8f);
        const float denom = fmaxf(2.0f + dap + dan, 1e-8f);
        acc += (jl == 0) ? (__logf(denom) - __logf(numer)) : 0.0f;
    }
    #pragma unroll
    for (int off = 1; off < 64; off <<= 1)
        acc += __shfl_xor(acc, off, 64);
    __shared__ float wsum[4];
    if (lane == 0) wsum[wib] = acc;
    __syncthreads();
    if (threadIdx.x == 0)
        atomicAdd(out, wsum[0] + wsum[1] + wsum[2] + wsum[3]);
}

extern "C" void kernel_launch(void* const* d_in, const int* in_sizes, int n_in,
                              void* d_out, int out_size, void* d_ws, size_t ws_size,
                              hipStream_t stream) {
    const float* x  = (const float*)d_in[0];
    const int* trip = (const int*)d_in[1];
    float* out      = (float*)d_out;
    const int T     = in_sizes[1] / 3;
    const int nrows = in_sizes[0] / DIM;

    const size_t xqs_bytes = (size_t)nrows * (DIM / 2);   // 1 MB slice-major table
    if (nrows == NR && ws_size >= xqs_bytes) {
        uint32_t* xqs = (uint32_t*)d_ws;
        const int cblocks = (nrows * 4 + 255) / 256;
        prep_q4s_kernel<<<cblocks, 256, 0, stream>>>((const float4*)x, xqs, out, nrows);
        const int blocks = (T + 2047) / 2048;             // 512 thr x 4 triplets
        triplet_lds2_kernel<<<blocks, 512, 0, stream>>>(xqs, trip, out, T);
    } else {
        (void)hipMemsetAsync(out, 0, sizeof(float), stream);
        triplet_f32_kernel<<<2048, 256, 0, stream>>>(x, trip, out, T);
    }
}